// Round 12
// baseline (59.905 us; speedup 1.0000x reference)
//
#include <hip/hip_runtime.h>

#define IMG 28
#define FLATK 784     // 28*28
#define OHW 26
#define FLAT 676      // 26*26
#define HID 100
#define NCLS 10
#define KP 800        // K padded to 25*32
#define BM 128        // rows per block (4 waves x 32 rows, mf=2)

typedef __attribute__((ext_vector_type(8))) short bfrag;   // 8 bf16 (4 VGPR)
typedef __attribute__((ext_vector_type(4))) float f32x4;
typedef __attribute__((ext_vector_type(4))) unsigned int u32x4;

__device__ __forceinline__ unsigned short f2bf(float f) {
    unsigned u = __float_as_uint(f);
    u = (u + 0x7fffu + ((u >> 16) & 1u)) >> 16;   // RNE
    return (unsigned short)u;
}

// Kernel 1: fold conv into fc1 -> bf16 W1eff [128 n][800 k] (zero-padded),
// and w2 -> bf16 [16 n][128 k] (zero-padded).
__global__ void build_weights(const float* __restrict__ conv_w,
                              const float* __restrict__ w1,
                              const float* __restrict__ w2,
                              unsigned short* __restrict__ w1b,
                              unsigned short* __restrict__ w2b) {
    int idx = blockIdx.x * blockDim.x + threadIdx.x;
    if (idx < 128 * KP) {
        int n = idx / KP, k = idx - n * KP;
        float val = 0.f;
        if (n < HID && k < FLATK) {
            int qr = k / IMG, qc = k % IMG;
            #pragma unroll
            for (int i = 0; i < 3; ++i) {
                int r = qr - i;
                if (r < 0 || r >= OHW) continue;
                #pragma unroll
                for (int j = 0; j < 3; ++j) {
                    int c = qc - j;
                    if (c < 0 || c >= OHW) continue;
                    val += conv_w[i * 3 + j] * w1[n * FLAT + r * OHW + c];
                }
            }
        }
        w1b[idx] = f2bf(val);
    } else {
        int t = idx - 128 * KP;
        if (t < 16 * 128) {
            int n = t >> 7, k = t & 127;
            float v = (n < NCLS && k < HID) ? w2[n * HID + k] : 0.f;
            w2b[t] = f2bf(v);
        }
    }
}

// load step S's A-fragments (both mf rows) into pre[PH]; PH,S literal ->
// SROA-promotes to registers (no scratch).
#define LOADA(PH, S) do {                                                      \
    int k_ = (S) * 32 + (khi << 3);                                            \
    if (k_ >= FLATK) k_ -= FLATK;  /* S=24 pad lanes: in-row garbage, B=0 */   \
    pre[PH][0] = *(const f32x4*)(xr0 + k_);                                    \
    pre[PH][1] = *(const f32x4*)(xr0 + k_ + 4);                                \
    pre[PH][2] = *(const f32x4*)(xr1 + k_);                                    \
    pre[PH][3] = *(const f32x4*)(xr1 + k_ + 4);                                \
} while (0)

// prefetch step S's 8 B-fragments into bw[PH] (L2-hot w1b); literal indices
#define LOADB(PH, S) do {                                                      \
    _Pragma("unroll")                                                          \
    for (int nt = 0; nt < 8; ++nt)                                             \
        bw[PH][nt] = *(const bfrag*)(w1b + (size_t)((nt << 4) + r15) * KP      \
                                     + (S) * 32 + (khi << 3));                 \
} while (0)

// consume step S: cvt_pk from pre[PA] -> 2 A-fragments, MFMA with bw[PB]
#define COMP(PA, PB, S) do {                                                   \
    union { u32x4 u; bfrag b; } a0_, a1_;                                      \
    asm("v_cvt_pk_bf16_f32 %0, %1, %2" : "=v"(a0_.u.x) : "v"(pre[PA][0].x), "v"(pre[PA][0].y)); \
    asm("v_cvt_pk_bf16_f32 %0, %1, %2" : "=v"(a0_.u.y) : "v"(pre[PA][0].z), "v"(pre[PA][0].w)); \
    asm("v_cvt_pk_bf16_f32 %0, %1, %2" : "=v"(a0_.u.z) : "v"(pre[PA][1].x), "v"(pre[PA][1].y)); \
    asm("v_cvt_pk_bf16_f32 %0, %1, %2" : "=v"(a0_.u.w) : "v"(pre[PA][1].z), "v"(pre[PA][1].w)); \
    asm("v_cvt_pk_bf16_f32 %0, %1, %2" : "=v"(a1_.u.x) : "v"(pre[PA][2].x), "v"(pre[PA][2].y)); \
    asm("v_cvt_pk_bf16_f32 %0, %1, %2" : "=v"(a1_.u.y) : "v"(pre[PA][2].z), "v"(pre[PA][2].w)); \
    asm("v_cvt_pk_bf16_f32 %0, %1, %2" : "=v"(a1_.u.z) : "v"(pre[PA][3].x), "v"(pre[PA][3].y)); \
    asm("v_cvt_pk_bf16_f32 %0, %1, %2" : "=v"(a1_.u.w) : "v"(pre[PA][3].z), "v"(pre[PA][3].w)); \
    _Pragma("unroll")                                                          \
    for (int nt = 0; nt < 8; ++nt) {                                           \
        acc0[nt] = __builtin_amdgcn_mfma_f32_16x16x32_bf16(a0_.b, bw[PB][nt], acc0[nt], 0, 0, 0); \
        acc1[nt] = __builtin_amdgcn_mfma_f32_16x16x32_bf16(a1_.b, bw[PB][nt], acc1[nt], 0, 0, 0); \
    }                                                                          \
} while (0)

// Kernel 2: barrier-free main loop (no LDS/syncs/waitcnts in main loop).
// 4 waves x 32 rows; A global->reg depth-4 ring; B 2-phase prefetch (issued
// 2 steps ahead); LDS only for the h1 transpose.
__global__ __launch_bounds__(256) void fused_fwd(
    const float* __restrict__ x,              // [65536][784] f32
    const unsigned short* __restrict__ w1b,   // [128][800] bf16
    const float* __restrict__ b1,             // [100]
    const unsigned short* __restrict__ w2b,   // [16][128] bf16
    const float* __restrict__ b2,             // [10]
    float* __restrict__ out)                  // [65536][10] f32
{
    __shared__ unsigned short H1[BM][136];    // 34816 B, epilogue only

    const int tid  = threadIdx.x;
    const int lane = tid & 63;
    const int wv   = tid >> 6;       // 0..3
    const int r15  = lane & 15;
    const int khi  = lane >> 4;      // 0..3 (k-slice *8)
    const int row0 = blockIdx.x * BM;

    // A rows: lane holds row r15 of mf0 slab and row 16+r15 of mf1 slab
    const float* xr0 = x + (size_t)(row0 + (wv << 5) + r15) * FLATK;
    const float* xr1 = xr0 + 16 * FLATK;

    f32x4 acc0[8], acc1[8];
    #pragma unroll
    for (int n = 0; n < 8; ++n) {
        acc0[n] = f32x4{0.f, 0.f, 0.f, 0.f};
        acc1[n] = f32x4{0.f, 0.f, 0.f, 0.f};
    }

    f32x4 pre[4][4];   // depth-4 A ring (literal indices only)
    bfrag bw[2][8];    // 2-phase B prefetch (literal indices only)

    LOADA(0, 0); LOADA(1, 1); LOADA(2, 2); LOADA(3, 3);
    LOADB(0, 0); LOADB(1, 1);

    COMP(0, 0, 0);  LOADA(0, 4);  LOADB(0, 2);
    COMP(1, 1, 1);  LOADA(1, 5);  LOADB(1, 3);
    COMP(2, 0, 2);  LOADA(2, 6);  LOADB(0, 4);
    COMP(3, 1, 3);  LOADA(3, 7);  LOADB(1, 5);
    COMP(0, 0, 4);  LOADA(0, 8);  LOADB(0, 6);
    COMP(1, 1, 5);  LOADA(1, 9);  LOADB(1, 7);
    COMP(2, 0, 6);  LOADA(2, 10); LOADB(0, 8);
    COMP(3, 1, 7);  LOADA(3, 11); LOADB(1, 9);
    COMP(0, 0, 8);  LOADA(0, 12); LOADB(0, 10);
    COMP(1, 1, 9);  LOADA(1, 13); LOADB(1, 11);
    COMP(2, 0, 10); LOADA(2, 14); LOADB(0, 12);
    COMP(3, 1, 11); LOADA(3, 15); LOADB(1, 13);
    COMP(0, 0, 12); LOADA(0, 16); LOADB(0, 14);
    COMP(1, 1, 13); LOADA(1, 17); LOADB(1, 15);
    COMP(2, 0, 14); LOADA(2, 18); LOADB(0, 16);
    COMP(3, 1, 15); LOADA(3, 19); LOADB(1, 17);
    COMP(0, 0, 16); LOADA(0, 20); LOADB(0, 18);
    COMP(1, 1, 17); LOADA(1, 21); LOADB(1, 19);
    COMP(2, 0, 18); LOADA(2, 22); LOADB(0, 20);
    COMP(3, 1, 19); LOADA(3, 23); LOADB(1, 21);
    COMP(0, 0, 20); LOADA(0, 24); LOADB(0, 22);
    COMP(1, 1, 21);               LOADB(1, 23);
    COMP(2, 0, 22);               LOADB(0, 24);
    COMP(3, 1, 23);
    COMP(0, 0, 24);

    // epilogue 1: bias + relu -> bf16 h1 in LDS [128][136]
    #pragma unroll
    for (int nt = 0; nt < 8; ++nt) {
        int col = (nt << 4) + r15;
        float bias = (col < HID) ? b1[col] : 0.f;
        int rb0 = (wv << 5) + (khi << 2);
        #pragma unroll
        for (int q = 0; q < 4; ++q) {
            float v0 = acc0[nt][q] + bias;
            float v1 = acc1[nt][q] + bias;
            H1[rb0 + q][col]      = f2bf(fmaxf(v0, 0.f));
            H1[rb0 + 16 + q][col] = f2bf(fmaxf(v1, 0.f));
        }
    }
    __syncthreads();

    // layer 2: [128 rows] x [16 cols] over K=128 (pad cols/k are exact zeros)
    f32x4 acc2[2] = {f32x4{0.f,0.f,0.f,0.f}, f32x4{0.f,0.f,0.f,0.f}};
    #pragma unroll
    for (int ks = 0; ks < 4; ++ks) {
        const bfrag bwv = *(const bfrag*)(w2b + r15 * 128 + (ks << 5) + (khi << 3));
        #pragma unroll
        for (int mf = 0; mf < 2; ++mf) {
            int r = (wv << 5) + (mf << 4) + r15;
            const bfrag ah = *(const bfrag*)&H1[r][(ks << 5) + (khi << 3)];
            acc2[mf] = __builtin_amdgcn_mfma_f32_16x16x32_bf16(ah, bwv, acc2[mf], 0, 0, 0);
        }
    }

    if (r15 < NCLS) {
        float bias2 = b2[r15];
        #pragma unroll
        for (int mf = 0; mf < 2; ++mf) {
            int rbase = row0 + (wv << 5) + (mf << 4) + (khi << 2);
            #pragma unroll
            for (int q = 0; q < 4; ++q)
                out[(size_t)(rbase + q) * NCLS + r15] = acc2[mf][q] + bias2;
        }
    }
}

extern "C" void kernel_launch(void* const* d_in, const int* in_sizes, int n_in,
                              void* d_out, int out_size, void* d_ws, size_t ws_size,
                              hipStream_t stream) {
    const float* x      = (const float*)d_in[0];
    const float* conv_w = (const float*)d_in[1];
    const float* w1     = (const float*)d_in[2];
    const float* b1     = (const float*)d_in[3];
    const float* w2     = (const float*)d_in[4];
    const float* b2     = (const float*)d_in[5];
    float* out = (float*)d_out;

    unsigned short* w1b = (unsigned short*)d_ws;   // 128*800*2 = 204.8 KB
    unsigned short* w2b = w1b + 128 * KP;          // 16*128*2  = 4 KB

    build_weights<<<(128 * KP + 16 * 128 + 255) / 256, 256, 0, stream>>>(conv_w, w1, w2, w1b, w2b);
    fused_fwd<<<65536 / BM, 256, 0, stream>>>(x, w1b, b1, w2b, b2, out);
}